// Round 7
// baseline (718.795 us; speedup 1.0000x reference)
//
#include <hip/hip_runtime.h>
#include <hip/hip_bf16.h>

// Problem constants (fixed-size problem)
constexpr int H      = 4;
constexpr int D_SUB  = 32;
constexpr int D_HID  = 128;
constexpr int B      = 100;
constexpr int N_PER  = 5000;
constexpr int N      = B * N_PER;        // 500000
constexpr int DEG    = 16;
constexpr int E      = N * DEG;          // 8000000
constexpr int E_PER  = N_PER * DEG;      // 80000
constexpr int K_PER  = 2500;
constexpr int NK     = B * K_PER;        // 250000

constexpr int EPB    = 4096;             // edges per block (compaction)
constexpr int EPT    = 16;               // edges per thread (compaction)
constexpr int NBLK_E = (E + EPB - 1) / EPB; // 1954

constexpr int SUBR   = 625;              // nodes per fused-score block (8 blocks/graph)
constexpr int LCAP   = 11640;            // LDS edge-list capacity (mean 10000 + skew 625 + slack)

constexpr int M      = 8192;             // bitonic size (pow2 >= N_PER)

// bijective XCD-chunked block swizzle: grid must be a multiple of 8
__device__ __forceinline__ int swz8(int bid, int chunk) {
    return (bid & 7) * chunk + (bid >> 3);
}

// padded LDS index for u64 keys: +1 slot per 8 -> breaks 64B-stride bank aliasing
__device__ __forceinline__ int ph(int i) { return i + (i >> 3); }

// ---------------- in-degree count: per-graph LDS histogram (once per graph) ----------------
__global__ __launch_bounds__(1024) void k_count(const int* __restrict__ col,
                                                int* __restrict__ cnt) {
    __shared__ int h[N_PER];  // 20 KB
    int lb = swz8(blockIdx.x, 25);       // 0..199, XCD-contiguous graphs
    int g = lb >> 1, half = lb & 1;
    for (int i = threadIdx.x; i < N_PER; i += 1024) h[i] = 0;
    __syncthreads();
    int ebase = g * E_PER + half * (E_PER / 2);
    int nbase = g * N_PER;
    for (int i = threadIdx.x; i < E_PER / 2; i += 1024)
        atomicAdd(&h[col[ebase + i] - nbase], 1);
    __syncthreads();
    for (int i = threadIdx.x; i < N_PER; i += 1024) {
        int v = h[i];
        if (v) atomicAdd(&cnt[nbase + i], v);
    }
}

// ---------------- fused: dis + adjacency-in-LDS + bit-exact score ----------------
// 8 blocks per graph; block owns a 625-node subrange; adjacency never touches HBM.
// P4 is wave-cooperative: each 32-lane half-wave sorts one node's <=32 entries via
// __shfl_xor bitonic (registers only, no per-thread arrays -> no scratch), then
// replays the reference's sequential left-fold via __shfl in ascending edge order.
__global__ __launch_bounds__(1024) void k_score_fused(const int* __restrict__ row,
                                                      const int* __restrict__ col,
                                                      const int* __restrict__ cnt,
                                                      const float* __restrict__ scW,
                                                      const float* __restrict__ scB,
                                                      float* __restrict__ score) {
    __shared__ float dis_l[N_PER];   // 20000 B
    __shared__ int   scanb[1024];    //  4096 B
    __shared__ int   offs_l[SUBR];   //  2500 B
    __shared__ int   curs_l[SUBR];   //  2500 B
    __shared__ int   list[LCAP];     // 46560 B   total 75656 B -> 2 blocks/CU
    int lb = swz8(blockIdx.x, 100);  // 0..799, XCD-contiguous (8 blocks of a graph share an XCD)
    int g = lb >> 3, q = lb & 7;
    int t = threadIdx.x;
    int nbase = g * N_PER;
    int ebase = g * E_PER;
    int lo = q * SUBR;

    // P1: dis for the whole graph into LDS (from global cnt, L2-hot)
    for (int j = t; j < N_PER; j += 1024) {
        float d = (float)(1 + cnt[nbase + j]);
        dis_l[j] = __fdiv_rn(1.0f, __fsqrt_rn(d));   // XLA pow(x,-0.5) -> 1/sqrt
    }
    // P2: scan of own-subrange degrees -> skewed compact list offsets
    int v = (t < SUBR) ? cnt[nbase + lo + t] : 0;
    scanb[t] = v;
    __syncthreads();
    for (int s = 1; s < 1024; s <<= 1) {
        int a = (t >= s) ? scanb[t - s] : 0;
        __syncthreads();
        scanb[t] += a;
        __syncthreads();
    }
    if (t < SUBR) { offs_l[t] = scanb[t] - v + t; curs_l[t] = 0; }  // +t bank skew
    __syncthreads();

    // P3: stream graph edges; append matching ones, packed (e_local<<13)|row_local
    for (int i = t; i < E_PER; i += 1024) {
        int e = ebase + i;
        int cl = col[e] - nbase;
        unsigned d = (unsigned)(cl - lo);
        if (d < (unsigned)SUBR) {
            int slot = atomicAdd(&curs_l[d], 1);
            int pos = offs_l[d] + slot;
            if (pos < LCAP) list[pos] = (i << 13) | (row[e] - nbase);
        }
    }
    __syncthreads();

    // P4: wave-cooperative sort + bit-exact sequential fold
    float w  = scW[0];
    float sb = scB[0];
    int lane = t & 63;
    int wid  = t >> 6;          // wave id 0..15
    int sub  = lane & 31;       // lane within half-wave
    int half = lane >> 5;       // which node of the pair
    for (int pr = wid; pr < (SUBR + 1) / 2; pr += 16) {
        int n = 2 * pr + half;
        bool valid_n = (n < SUBR);
        int kk = 0, base = 0;
        if (valid_n) {
            kk = curs_l[n];
            base = offs_l[n];
            if (base + kk > LCAP) kk = 0;   // overflow guard (probability ~0)
        }
        float dv = valid_n ? dis_l[lo + n] : 0.0f;

        // fast path: kk <= 32, one entry per lane
        int pv = 0x7FFFFFFF;
        if (valid_n && kk <= 32 && sub < kk) pv = list[base + sub];
        // 32-wide bitonic sort, ascending (padding INT_MAX sorts last)
#pragma unroll
        for (int k2 = 2; k2 <= 32; k2 <<= 1) {
#pragma unroll
            for (int j = k2 >> 1; j > 0; j >>= 1) {
                int o = __shfl_xor(pv, j, 32);
                bool up = ((sub & k2) == 0);
                bool keepMin = (((sub & j) == 0) == up);
                int mn = min(pv, o), mx = max(pv, o);
                pv = keepMin ? mn : mx;
            }
        }
        float term = 0.0f;
        if (pv != 0x7FFFFFFF)
            term = __fmul_rn(w, __fmul_rn(dis_l[pv & 8191], dv));
        // sequential left-fold in sorted (ascending edge id) order — reference order
        float s = 0.0f;
#pragma unroll
        for (int j = 0; j < 32; j++) {
            float tj = __shfl(term, j, 32);
            if (j < kk) s = __fadd_rn(s, tj);
        }
        if (valid_n && sub == 0) {
            if (kk > 32) {
                // rare fallback (deg > 32): serial LDS insertion sort + fold
                for (int i = 1; i < kk; i++) {
                    int key = list[base + i];
                    int j = i - 1;
                    while (j >= 0 && list[base + j] > key) { list[base + j + 1] = list[base + j]; j--; }
                    list[base + j + 1] = key;
                }
                s = 0.0f;
                for (int i = 0; i < kk; i++) {
                    int rl = list[base + i] & 8191;
                    s = __fadd_rn(s, __fmul_rn(w, __fmul_rn(dis_l[rl], dv)));
                }
            }
            s = __fadd_rn(s, __fmul_rn(w, __fmul_rn(dv, dv)));  // self-loop term
            s = __fadd_rn(s, sb);
            score[nbase + lo + n] = s;
        }
    }
}

// ---------------- per-graph stable top-k: register-blocked bitonic sort ----------------
// u64 key = (~sortable(score) << 32) | idx  ->  ascending u64 == descending score,
// ties broken by lower index (jax.lax.top_k semantics).
__global__ __launch_bounds__(1024) void k_topk(const float* __restrict__ score,
                                               float* __restrict__ out_batch,
                                               float* __restrict__ out_perm,
                                               int* __restrict__ perm_i,
                                               int* __restrict__ n_idx) {
    __shared__ unsigned long long keys[M + (M >> 3)];  // 9216 u64 = 73728 B (padded)
    int b = blockIdx.x, t = threadIdx.x;
    int base = 8 * t;

    // load 8 contiguous elements into registers, build keys
    unsigned long long v[8];
    if (t < 625) {   // 8*625 = 5000 = N_PER exactly
        const float4* s4 = (const float4*)(score + b * N_PER + base);
        float4 f0 = s4[0], f1 = s4[1];
        float fs[8] = {f0.x, f0.y, f0.z, f0.w, f1.x, f1.y, f1.z, f1.w};
#pragma unroll
        for (int m = 0; m < 8; m++) {
            unsigned u = __float_as_uint(fs[m]);
            unsigned asc = u ^ ((u & 0x80000000u) ? 0xFFFFFFFFu : 0x80000000u);
            v[m] = ((unsigned long long)(~asc) << 32) | (unsigned)(base + m);
        }
    } else {
#pragma unroll
        for (int m = 0; m < 8; m++) v[m] = ~0ull;  // padding sorts last
    }

#define CEV(x, y, up) { if ((v[x] > v[y]) == (up)) { unsigned long long tmp = v[x]; v[x] = v[y]; v[y] = tmp; } }
    // in-register bitonic stages k=2,4,8 (directions from global position 8t+m)
    CEV(0, 1, true)  CEV(2, 3, false) CEV(4, 5, true)  CEV(6, 7, false)      // k=2
    CEV(0, 2, true)  CEV(1, 3, true)  CEV(4, 6, false) CEV(5, 7, false)      // k=4 j=2
    CEV(0, 1, true)  CEV(2, 3, true)  CEV(4, 5, false) CEV(6, 7, false)      // k=4 j=1
    {
        bool u8 = ((t & 1) == 0);                                            // k=8
        CEV(0, 4, u8) CEV(1, 5, u8) CEV(2, 6, u8) CEV(3, 7, u8)
        CEV(0, 2, u8) CEV(1, 3, u8) CEV(4, 6, u8) CEV(5, 7, u8)
        CEV(0, 1, u8) CEV(2, 3, u8) CEV(4, 5, u8) CEV(6, 7, u8)
    }
#pragma unroll
    for (int m = 0; m < 8; m++) keys[ph(base + m)] = v[m];
    __syncthreads();

    // stages k=16..8192: LDS passes j=k/2..8, then fused register pass j=4,2,1.
    // Final stage: after j=4096 the lower half holds the 4096 smallest keys; sort only it.
    for (int k = 16; k <= M; k <<= 1) {
        bool last = (k == M);
        for (int j = k >> 1; j >= 8; j >>= 1) {
            int np = (last && j < (M >> 1)) ? (M >> 2) : (M >> 1);
            for (int p = t; p < np; p += 1024) {
                int i = ((p & ~(j - 1)) << 1) | (p & (j - 1));
                int ip = i | j;
                bool up = ((i & k) == 0);
                unsigned long long a = keys[ph(i)];
                unsigned long long c = keys[ph(ip)];
                if ((a > c) == up) { keys[ph(i)] = c; keys[ph(ip)] = a; }
            }
            __syncthreads();
        }
        int nb = last ? 512 : 1024;   // last stage: register pass only on [0,4096)
        if (t < nb) {
            bool up = ((base & k) == 0);
            unsigned long long w[8];
#pragma unroll
            for (int m = 0; m < 8; m++) w[m] = keys[ph(base + m)];
#define CEW(x, y) { if ((w[x] > w[y]) == up) { unsigned long long tmp = w[x]; w[x] = w[y]; w[y] = tmp; } }
            CEW(0, 4) CEW(1, 5) CEW(2, 6) CEW(3, 7)   // j=4
            CEW(0, 2) CEW(1, 3) CEW(4, 6) CEW(5, 7)   // j=2
            CEW(0, 1) CEW(2, 3) CEW(4, 5) CEW(6, 7)   // j=1
#pragma unroll
            for (int m = 0; m < 8; m++) keys[ph(base + m)] = w[m];
        }
        __syncthreads();
    }

    for (int r = t; r < K_PER; r += 1024) {
        unsigned long long key = keys[ph(r)];
        int idx = (int)(key & 0xFFFFFFFFull);
        int gl = b * N_PER + idx;
        int ni = b * K_PER + r;
        perm_i[ni] = gl;
        n_idx[gl] = ni;
        out_perm[ni] = (float)gl;
        out_batch[ni] = (float)b;
    }
}

// ---------------- x_new = x[perm] * tanh(score[perm]) ----------------
__global__ void k_xnew(const float4* __restrict__ x4, const float* __restrict__ score,
                       const int* __restrict__ perm_i, float4* __restrict__ out4) {
    int tid = blockIdx.x * blockDim.x + threadIdx.x;
    if (tid >= NK * (D_HID / 4)) return;
    int i = tid >> 5;       // row (D_HID/4 = 32 float4 per row)
    int c = tid & 31;
    int g = perm_i[i];
    float ts = tanhf(score[g]);
    float4 v = x4[(long)g * 32 + c];
    v.x *= ts; v.y *= ts; v.z *= ts; v.w *= ts;
    out4[tid] = v;
}

// ---------------- edge compaction: per-block keep counts ----------------
__global__ void k_keepcount(const int* __restrict__ row, const int* __restrict__ col,
                            const int* __restrict__ n_idx, int* __restrict__ bsum) {
    __shared__ int sh[256];
    int blk = blockIdx.x, t = threadIdx.x;
    int base = blk * EPB + t * EPT;
    int cnt = 0;
#pragma unroll
    for (int i = 0; i < EPT; i++) {
        int e = base + i;
        if (e < E) {
            if (n_idx[row[e]] >= 0 && n_idx[col[e]] >= 0) cnt++;
        }
    }
    sh[t] = cnt;
    __syncthreads();
    for (int s = 128; s > 0; s >>= 1) {
        if (t < s) sh[t] += sh[t + s];
        __syncthreads();
    }
    if (t == 0) bsum[blk] = sh[0];
}

// ---------------- scan of per-block counts (single block) ----------------
__global__ void k_scanblocks(const int* __restrict__ bsum, int* __restrict__ boff,
                             int* __restrict__ total) {
    __shared__ int sh[256];
    __shared__ int carry;
    int t = threadIdx.x;
    if (t == 0) carry = 0;
    __syncthreads();
    for (int c0 = 0; c0 < NBLK_E; c0 += 256) {
        int i = c0 + t;
        int v = (i < NBLK_E) ? bsum[i] : 0;
        sh[t] = v;
        __syncthreads();
        for (int s = 1; s < 256; s <<= 1) {
            int a = (t >= s) ? sh[t - s] : 0;
            __syncthreads();
            sh[t] += a;
            __syncthreads();
        }
        if (i < NBLK_E) boff[i] = carry + sh[t] - v;
        __syncthreads();
        if (t == 255) carry += sh[255];
        __syncthreads();
    }
    if (t == 0) total[0] = carry;
}

// ---------------- order-preserving scatter of kept edges (reindexed, as float) ----------------
__global__ void k_scatter(const int* __restrict__ row, const int* __restrict__ col,
                          const int* __restrict__ n_idx, const int* __restrict__ boff,
                          float* __restrict__ oe0, float* __restrict__ oe1) {
    __shared__ int sh[256];
    int blk = blockIdx.x, t = threadIdx.x;
    int base = blk * EPB + t * EPT;
    int rr[EPT], cc[EPT];
    int cnt = 0;
#pragma unroll
    for (int i = 0; i < EPT; i++) {
        int e = base + i;
        int rv = -1, cv = -1;
        if (e < E) { rv = n_idx[row[e]]; cv = n_idx[col[e]]; }
        rr[i] = rv; cc[i] = cv;
        if (rv >= 0 && cv >= 0) cnt++;
    }
    sh[t] = cnt;
    __syncthreads();
    for (int s = 1; s < 256; s <<= 1) {
        int a = (t >= s) ? sh[t - s] : 0;
        __syncthreads();
        sh[t] += a;
        __syncthreads();
    }
    int pos = boff[blk] + sh[t] - cnt;
#pragma unroll
    for (int i = 0; i < EPT; i++) {
        if (rr[i] >= 0 && cc[i] >= 0) {
            oe0[pos] = (float)rr[i];
            oe1[pos] = (float)cc[i];
            pos++;
        }
    }
}

// ---------------- fill tail of edge output with -1 ----------------
__global__ void k_filltail(const int* __restrict__ total, float* __restrict__ oe0,
                           float* __restrict__ oe1) {
    int cnt = total[0];
    int i = blockIdx.x * blockDim.x + threadIdx.x;
    int stride = gridDim.x * blockDim.x;
    for (; i < E; i += stride) {
        if (i >= cnt) { oe0[i] = -1.0f; oe1[i] = -1.0f; }
    }
}

extern "C" void kernel_launch(void* const* d_in, const int* in_sizes, int n_in,
                              void* d_out, int out_size, void* d_ws, size_t ws_size,
                              hipStream_t stream) {
    const float* x   = (const float*)d_in[0];
    const float* scW = (const float*)d_in[4];
    const float* scB = (const float*)d_in[5];
    const int*   edge = (const int*)d_in[6];
    const int*   row = edge;
    const int*   col = edge + E;

    // workspace layout (ints/floats, 4B each)
    int*   ws_i    = (int*)d_ws;
    int*   deg_cnt = ws_i;                   // N
    float* score   = (float*)(ws_i + N);     // N
    int*   n_idx   = ws_i + 2 * N;           // N
    int*   perm_i  = ws_i + 3 * N;           // NK
    int*   bsum    = ws_i + 3 * N + NK;      // NBLK_E
    int*   boff    = bsum + NBLK_E;          // NBLK_E
    int*   total   = boff + NBLK_E;          // 1

    // output layout: x_new [NK, D_HID] | edge_new [2, E] | batch_new [NK] | perm [NK]
    float* out_x     = (float*)d_out;
    float* oe0       = out_x + (size_t)NK * D_HID;
    float* oe1       = oe0 + E;
    float* out_batch = oe1 + E;
    float* out_perm  = out_batch + NK;

    hipMemsetAsync(deg_cnt, 0, (size_t)N * sizeof(int), stream);
    hipMemsetAsync(n_idx, 0xFF, (size_t)N * sizeof(int), stream);  // -1

    k_count<<<200, 1024, 0, stream>>>(col, deg_cnt);
    k_score_fused<<<800, 1024, 0, stream>>>(row, col, deg_cnt, scW, scB, score);
    k_topk<<<B, 1024, 0, stream>>>(score, out_batch, out_perm, perm_i, n_idx);
    k_xnew<<<(NK * (D_HID / 4) + 255) / 256, 256, 0, stream>>>((const float4*)x, score, perm_i,
                                                               (float4*)out_x);
    k_keepcount<<<NBLK_E, 256, 0, stream>>>(row, col, n_idx, bsum);
    k_scanblocks<<<1, 256, 0, stream>>>(bsum, boff, total);
    k_scatter<<<NBLK_E, 256, 0, stream>>>(row, col, n_idx, boff, oe0, oe1);
    k_filltail<<<4096, 256, 0, stream>>>(total, oe0, oe1);
}

// Round 8
// 387.204 us; speedup vs baseline: 1.8564x; 1.8564x over previous
//
#include <hip/hip_runtime.h>
#include <hip/hip_bf16.h>

// Problem constants (fixed-size problem)
constexpr int H      = 4;
constexpr int D_SUB  = 32;
constexpr int D_HID  = 128;
constexpr int B      = 100;
constexpr int N_PER  = 5000;
constexpr int N      = B * N_PER;        // 500000
constexpr int DEG    = 16;
constexpr int E      = N * DEG;          // 8000000
constexpr int E_PER  = N_PER * DEG;      // 80000
constexpr int K_PER  = 2500;
constexpr int NK     = B * K_PER;        // 250000

constexpr int EPB    = 4096;             // edges per block (compaction)
constexpr int EPT    = 16;               // edges per thread (compaction)
constexpr int NBLK_E = (E + EPB - 1) / EPB; // 1954

constexpr int SUBR   = 625;              // nodes per fused-score block (8 blocks/graph)
constexpr int LCAP   = 11640;            // LDS edge-list capacity (mean 10000 + skew 625 + slack)

constexpr int M      = 8192;             // bitonic size (pow2 >= N_PER)

// decoupled-lookback status flags
constexpr unsigned long long FLG_A = 1ull << 62;   // aggregate ready
constexpr unsigned long long FLG_I = 2ull << 62;   // inclusive ready

// bijective XCD-chunked block swizzle: grid must be a multiple of 8
__device__ __forceinline__ int swz8(int bid, int chunk) {
    return (bid & 7) * chunk + (bid >> 3);
}

// padded LDS index for u64 keys: +1 slot per 8 -> breaks 64B-stride bank aliasing
__device__ __forceinline__ int ph(int i) { return i + (i >> 3); }

// ---------------- in-degree count: per-graph LDS histogram ----------------
__global__ __launch_bounds__(1024) void k_count(const int* __restrict__ col,
                                                int* __restrict__ cnt) {
    __shared__ int h[N_PER];  // 20 KB
    int lb = swz8(blockIdx.x, 25);       // 0..199, XCD-contiguous graphs
    int g = lb >> 1, half = lb & 1;
    for (int i = threadIdx.x; i < N_PER; i += 1024) h[i] = 0;
    __syncthreads();
    int ebase = g * E_PER + half * (E_PER / 2);
    int nbase = g * N_PER;
    const int4* c4 = (const int4*)(col + ebase);    // 16B-aligned (ebase*4 % 16 == 0)
    for (int i = threadIdx.x; i < E_PER / 2 / 4; i += 1024) {
        int4 v = c4[i];
        atomicAdd(&h[v.x - nbase], 1);
        atomicAdd(&h[v.y - nbase], 1);
        atomicAdd(&h[v.z - nbase], 1);
        atomicAdd(&h[v.w - nbase], 1);
    }
    __syncthreads();
    for (int i = threadIdx.x; i < N_PER; i += 1024) {
        int v = h[i];
        if (v) atomicAdd(&cnt[nbase + i], v);
    }
}

// ---------------- fused: dis + adjacency-in-LDS + bit-exact score ----------------
// 8 blocks per graph; block owns a 625-node subrange; adjacency never touches HBM.
// P4 visits each node's entries in ascending edge id via a selection-fold:
// k passes of k INDEPENDENT LDS reads (running min > prev) -- no dependent RMW
// chains, no per-thread arrays, identical __fadd_rn sequence to the reference.
__global__ __launch_bounds__(1024) void k_score_fused(const int* __restrict__ row,
                                                      const int* __restrict__ col,
                                                      const int* __restrict__ cnt,
                                                      const float* __restrict__ scW,
                                                      const float* __restrict__ scB,
                                                      float* __restrict__ score) {
    __shared__ float dis_l[N_PER];   // 20000 B
    __shared__ int   scanb[1024];    //  4096 B
    __shared__ int   offs_l[SUBR];   //  2500 B
    __shared__ int   curs_l[SUBR];   //  2500 B
    __shared__ int   list[LCAP];     // 46560 B   total 75656 B -> 2 blocks/CU
    int lb = swz8(blockIdx.x, 100);  // 0..799, XCD-contiguous (8 blocks of a graph share an XCD)
    int g = lb >> 3, q = lb & 7;
    int t = threadIdx.x;
    int nbase = g * N_PER;
    int ebase = g * E_PER;
    int lo = q * SUBR;

    // P1: dis for the whole graph into LDS (from global cnt, L2-hot)
    for (int j = t; j < N_PER; j += 1024) {
        float d = (float)(1 + cnt[nbase + j]);
        dis_l[j] = __fdiv_rn(1.0f, __fsqrt_rn(d));   // XLA pow(x,-0.5) -> 1/sqrt
    }
    // P2: scan of own-subrange degrees -> skewed compact list offsets
    int v = (t < SUBR) ? cnt[nbase + lo + t] : 0;
    scanb[t] = v;
    __syncthreads();
    for (int s = 1; s < 1024; s <<= 1) {
        int a = (t >= s) ? scanb[t - s] : 0;
        __syncthreads();
        scanb[t] += a;
        __syncthreads();
    }
    if (t < SUBR) { offs_l[t] = scanb[t] - v + t; curs_l[t] = 0; }  // +t bank skew
    __syncthreads();

    // P3: stream graph edges (int4 col); append matches, packed (e_local<<13)|row_local
    const int4* c4 = (const int4*)(col + ebase);    // 16B-aligned
    for (int i4 = t; i4 < E_PER / 4; i4 += 1024) {
        int4 cv = c4[i4];
        int i0 = 4 * i4;
#pragma unroll
        for (int m = 0; m < 4; m++) {
            int cl = ((m == 0) ? cv.x : (m == 1) ? cv.y : (m == 2) ? cv.z : cv.w) - nbase;
            unsigned d = (unsigned)(cl - lo);
            if (d < (unsigned)SUBR) {
                int i = i0 + m;
                int slot = atomicAdd(&curs_l[d], 1);
                int pos = offs_l[d] + slot;
                if (pos < LCAP) list[pos] = (i << 13) | (row[ebase + i] - nbase);
            }
        }
    }
    __syncthreads();

    // P4: selection-fold in ascending packed (edge id) order -- bit-exact reference order
    if (t < SUBR) {
        int base = offs_l[t];
        int k = v;
        if (base + k > LCAP) k = 0;          // overflow guard (probability ~0)
        float w = scW[0];
        float dv = dis_l[lo + t];
        float s = 0.0f;
        int prev = -1;                        // packed values are >= 0 and unique
        for (int r = 0; r < k; r++) {
            int mn = 0x7FFFFFFF;
            for (int j = 0; j < k; j++) {
                int val = list[base + j];     // independent reads, no RMW chain
                if (val > prev && val < mn) mn = val;
            }
            prev = mn;
            s = __fadd_rn(s, __fmul_rn(w, __fmul_rn(dis_l[mn & 8191], dv)));
        }
        s = __fadd_rn(s, __fmul_rn(w, __fmul_rn(dv, dv)));  // self-loop term
        s = __fadd_rn(s, scB[0]);
        score[nbase + lo + t] = s;
    }
}

// ---------------- per-graph stable top-k: register-blocked bitonic sort ----------------
// u64 key = (~sortable(score) << 32) | idx  ->  ascending u64 == descending score,
// ties broken by lower index (jax.lax.top_k semantics).
__global__ __launch_bounds__(1024) void k_topk(const float* __restrict__ score,
                                               float* __restrict__ out_batch,
                                               float* __restrict__ out_perm,
                                               int* __restrict__ perm_i,
                                               int* __restrict__ n_idx) {
    __shared__ unsigned long long keys[M + (M >> 3)];  // 9216 u64 = 73728 B (padded)
    int b = blockIdx.x, t = threadIdx.x;
    int base = 8 * t;

    // load 8 contiguous elements into registers, build keys
    unsigned long long v[8];
    if (t < 625) {   // 8*625 = 5000 = N_PER exactly
        const float4* s4 = (const float4*)(score + b * N_PER + base);
        float4 f0 = s4[0], f1 = s4[1];
        float fs[8] = {f0.x, f0.y, f0.z, f0.w, f1.x, f1.y, f1.z, f1.w};
#pragma unroll
        for (int m = 0; m < 8; m++) {
            unsigned u = __float_as_uint(fs[m]);
            unsigned asc = u ^ ((u & 0x80000000u) ? 0xFFFFFFFFu : 0x80000000u);
            v[m] = ((unsigned long long)(~asc) << 32) | (unsigned)(base + m);
        }
    } else {
#pragma unroll
        for (int m = 0; m < 8; m++) v[m] = ~0ull;  // padding sorts last
    }

#define CEV(x, y, up) { if ((v[x] > v[y]) == (up)) { unsigned long long tmp = v[x]; v[x] = v[y]; v[y] = tmp; } }
    // in-register bitonic stages k=2,4,8 (directions from global position 8t+m)
    CEV(0, 1, true)  CEV(2, 3, false) CEV(4, 5, true)  CEV(6, 7, false)      // k=2
    CEV(0, 2, true)  CEV(1, 3, true)  CEV(4, 6, false) CEV(5, 7, false)      // k=4 j=2
    CEV(0, 1, true)  CEV(2, 3, true)  CEV(4, 5, false) CEV(6, 7, false)      // k=4 j=1
    {
        bool u8 = ((t & 1) == 0);                                            // k=8
        CEV(0, 4, u8) CEV(1, 5, u8) CEV(2, 6, u8) CEV(3, 7, u8)
        CEV(0, 2, u8) CEV(1, 3, u8) CEV(4, 6, u8) CEV(5, 7, u8)
        CEV(0, 1, u8) CEV(2, 3, u8) CEV(4, 5, u8) CEV(6, 7, u8)
    }
#pragma unroll
    for (int m = 0; m < 8; m++) keys[ph(base + m)] = v[m];
    __syncthreads();

    // stages k=16..8192: LDS passes j=k/2..8, then fused register pass j=4,2,1.
    // Final stage: after j=4096 the lower half holds the 4096 smallest keys; sort only it.
    for (int k = 16; k <= M; k <<= 1) {
        bool last = (k == M);
        for (int j = k >> 1; j >= 8; j >>= 1) {
            int np = (last && j < (M >> 1)) ? (M >> 2) : (M >> 1);
            for (int p = t; p < np; p += 1024) {
                int i = ((p & ~(j - 1)) << 1) | (p & (j - 1));
                int ip = i | j;
                bool up = ((i & k) == 0);
                unsigned long long a = keys[ph(i)];
                unsigned long long c = keys[ph(ip)];
                if ((a > c) == up) { keys[ph(i)] = c; keys[ph(ip)] = a; }
            }
            __syncthreads();
        }
        int nb = last ? 512 : 1024;   // last stage: register pass only on [0,4096)
        if (t < nb) {
            bool up = ((base & k) == 0);
            unsigned long long w[8];
#pragma unroll
            for (int m = 0; m < 8; m++) w[m] = keys[ph(base + m)];
#define CEW(x, y) { if ((w[x] > w[y]) == up) { unsigned long long tmp = w[x]; w[x] = w[y]; w[y] = tmp; } }
            CEW(0, 4) CEW(1, 5) CEW(2, 6) CEW(3, 7)   // j=4
            CEW(0, 2) CEW(1, 3) CEW(4, 6) CEW(5, 7)   // j=2
            CEW(0, 1) CEW(2, 3) CEW(4, 5) CEW(6, 7)   // j=1
#pragma unroll
            for (int m = 0; m < 8; m++) keys[ph(base + m)] = w[m];
        }
        __syncthreads();
    }

    for (int r = t; r < K_PER; r += 1024) {
        unsigned long long key = keys[ph(r)];
        int idx = (int)(key & 0xFFFFFFFFull);
        int gl = b * N_PER + idx;
        int ni = b * K_PER + r;
        perm_i[ni] = gl;
        n_idx[gl] = ni;
        out_perm[ni] = (float)gl;
        out_batch[ni] = (float)b;
    }
}

// ---------------- x_new = x[perm] * tanh(score[perm]) ----------------
__global__ void k_xnew(const float4* __restrict__ x4, const float* __restrict__ score,
                       const int* __restrict__ perm_i, float4* __restrict__ out4) {
    int tid = blockIdx.x * blockDim.x + threadIdx.x;
    if (tid >= NK * (D_HID / 4)) return;
    int i = tid >> 5;       // row (D_HID/4 = 32 float4 per row)
    int c = tid & 31;
    int g = perm_i[i];
    float ts = tanhf(score[g]);
    float4 v = x4[(long)g * 32 + c];
    v.x *= ts; v.y *= ts; v.z *= ts; v.w *= ts;
    out4[tid] = v;
}

// ---------------- prefill edge outputs with -1 (replaces filltail; no deps) ----------------
__global__ void k_prefill(float4* __restrict__ oe0, float4* __restrict__ oe1) {
    int i = blockIdx.x * blockDim.x + threadIdx.x;
    int stride = gridDim.x * blockDim.x;
    float4 m1 = make_float4(-1.0f, -1.0f, -1.0f, -1.0f);
    for (; i < E / 4; i += stride) { oe0[i] = m1; oe1[i] = m1; }
}

// ---------------- single-pass order-preserving edge compaction (decoupled lookback) ----------------
__global__ __launch_bounds__(256) void k_compact(const int* __restrict__ row,
                                                 const int* __restrict__ col,
                                                 const int* __restrict__ n_idx,
                                                 unsigned long long* __restrict__ status,
                                                 float* __restrict__ oe0,
                                                 float* __restrict__ oe1) {
    __shared__ int sh[256];
    __shared__ int excl_sh;
    int blk = blockIdx.x, t = threadIdx.x;
    int base = blk * EPB + t * EPT;
    int rr[EPT], cc[EPT];
    int cnt = 0;
#pragma unroll
    for (int i = 0; i < EPT; i++) {
        int e = base + i;
        int rv = -1, cv = -1;
        if (e < E) { rv = n_idx[row[e]]; cv = n_idx[col[e]]; }
        rr[i] = rv; cc[i] = cv;
        if (rv >= 0 && cv >= 0) cnt++;
    }
    sh[t] = cnt;
    __syncthreads();
    for (int s = 1; s < 256; s <<= 1) {
        int a = (t >= s) ? sh[t - s] : 0;
        __syncthreads();
        sh[t] += a;
        __syncthreads();
    }
    int incl = sh[t];
    int agg  = sh[255];
    if (t == 0) {
        if (blk == 0) {
            atomicExch(&status[0], FLG_I | (unsigned long long)(unsigned)agg);
            excl_sh = 0;
        } else {
            atomicExch(&status[blk], FLG_A | (unsigned long long)(unsigned)agg);
            unsigned long long ex = 0;
            for (int i = blk - 1; i >= 0; i--) {
                unsigned long long sv;
                do { sv = atomicAdd(&status[i], 0ull); } while (sv == 0ull);
                ex += (sv & 0xFFFFFFFFull);
                if (sv & FLG_I) break;
            }
            atomicExch(&status[blk], FLG_I | (ex + (unsigned long long)(unsigned)agg));
            excl_sh = (int)ex;
        }
    }
    __syncthreads();
    int pos = excl_sh + incl - cnt;
#pragma unroll
    for (int i = 0; i < EPT; i++) {
        if (rr[i] >= 0 && cc[i] >= 0) {
            oe0[pos] = (float)rr[i];
            oe1[pos] = (float)cc[i];
            pos++;
        }
    }
}

extern "C" void kernel_launch(void* const* d_in, const int* in_sizes, int n_in,
                              void* d_out, int out_size, void* d_ws, size_t ws_size,
                              hipStream_t stream) {
    const float* x   = (const float*)d_in[0];
    const float* scW = (const float*)d_in[4];
    const float* scB = (const float*)d_in[5];
    const int*   edge = (const int*)d_in[6];
    const int*   row = edge;
    const int*   col = edge + E;

    // workspace layout: status (u64, 8B-aligned at base) then ints/floats
    unsigned long long* status = (unsigned long long*)d_ws;   // NBLK_E
    int*   ws_i    = (int*)(status + NBLK_E);
    int*   deg_cnt = ws_i;                   // N
    float* score   = (float*)(ws_i + N);     // N
    int*   n_idx   = ws_i + 2 * N;           // N
    int*   perm_i  = ws_i + 3 * N;           // NK

    // output layout: x_new [NK, D_HID] | edge_new [2, E] | batch_new [NK] | perm [NK]
    float* out_x     = (float*)d_out;
    float* oe0       = out_x + (size_t)NK * D_HID;
    float* oe1       = oe0 + E;
    float* out_batch = oe1 + E;
    float* out_perm  = out_batch + NK;

    hipMemsetAsync(deg_cnt, 0, (size_t)N * sizeof(int), stream);
    hipMemsetAsync(n_idx, 0xFF, (size_t)N * sizeof(int), stream);  // -1
    hipMemsetAsync(status, 0, (size_t)NBLK_E * sizeof(unsigned long long), stream);

    k_prefill<<<2048, 256, 0, stream>>>((float4*)oe0, (float4*)oe1);
    k_count<<<200, 1024, 0, stream>>>(col, deg_cnt);
    k_score_fused<<<800, 1024, 0, stream>>>(row, col, deg_cnt, scW, scB, score);
    k_topk<<<B, 1024, 0, stream>>>(score, out_batch, out_perm, perm_i, n_idx);
    k_xnew<<<(NK * (D_HID / 4) + 255) / 256, 256, 0, stream>>>((const float4*)x, score, perm_i,
                                                               (float4*)out_x);
    k_compact<<<NBLK_E, 256, 0, stream>>>(row, col, n_idx, status, oe0, oe1);
}

// Round 9
// 335.899 us; speedup vs baseline: 2.1399x; 1.1527x over previous
//
#include <hip/hip_runtime.h>
#include <hip/hip_bf16.h>

// Problem constants (fixed-size problem)
constexpr int H      = 4;
constexpr int D_SUB  = 32;
constexpr int D_HID  = 128;
constexpr int B      = 100;
constexpr int N_PER  = 5000;
constexpr int N      = B * N_PER;        // 500000
constexpr int DEG    = 16;
constexpr int E      = N * DEG;          // 8000000
constexpr int E_PER  = N_PER * DEG;      // 80000
constexpr int K_PER  = 2500;
constexpr int NK     = B * K_PER;        // 250000

constexpr int EPB    = 4096;             // edges per block (compaction)
constexpr int EPT    = 16;               // edges per thread (compaction)
constexpr int NBLK_E = (E + EPB - 1) / EPB; // 1954

constexpr int SUBR   = 625;              // nodes per fused-score block (8 blocks/graph)
constexpr int LCAP   = 11640;            // LDS edge-list capacity (mean 10000 + skew 625 + slack)

constexpr int M      = 8192;             // bitonic size (pow2 >= N_PER)

// decoupled-lookback status flags
constexpr unsigned long long FLG_A = 1ull << 62;   // aggregate ready
constexpr unsigned long long FLG_I = 2ull << 62;   // inclusive ready

// bijective XCD-chunked block swizzle: grid must be a multiple of 8
__device__ __forceinline__ int swz8(int bid, int chunk) {
    return (bid & 7) * chunk + (bid >> 3);
}

// padded LDS index for u64 keys: +1 slot per 8 -> breaks 64B-stride bank aliasing
__device__ __forceinline__ int ph(int i) { return i + (i >> 3); }

// ---------------- in-degree count: per-graph LDS histogram ----------------
__global__ __launch_bounds__(1024) void k_count(const int* __restrict__ col,
                                                int* __restrict__ cnt) {
    __shared__ int h[N_PER];  // 20 KB
    int lb = swz8(blockIdx.x, 25);       // 0..199, XCD-contiguous graphs
    int g = lb >> 1, half = lb & 1;
    for (int i = threadIdx.x; i < N_PER; i += 1024) h[i] = 0;
    __syncthreads();
    int ebase = g * E_PER + half * (E_PER / 2);
    int nbase = g * N_PER;
    const int4* c4 = (const int4*)(col + ebase);    // 16B-aligned (ebase*4 % 16 == 0)
    for (int i = threadIdx.x; i < E_PER / 2 / 4; i += 1024) {
        int4 v = c4[i];
        atomicAdd(&h[v.x - nbase], 1);
        atomicAdd(&h[v.y - nbase], 1);
        atomicAdd(&h[v.z - nbase], 1);
        atomicAdd(&h[v.w - nbase], 1);
    }
    __syncthreads();
    for (int i = threadIdx.x; i < N_PER; i += 1024) {
        int v = h[i];
        if (v) atomicAdd(&cnt[nbase + i], v);
    }
}

// ---------------- dis = (1+deg)^-0.5, once per node (XLA pow(x,-0.5)->1/sqrt) ----------------
__global__ void k_dis(const int* __restrict__ cnt, float* __restrict__ dis) {
    int v = blockIdx.x * blockDim.x + threadIdx.x;
    if (v < N) {
        float d = (float)(1 + cnt[v]);
        dis[v] = __fdiv_rn(1.0f, __fsqrt_rn(d));
    }
}

// ---------------- fused: adjacency-in-LDS + bit-exact score ----------------
// 8 blocks per graph; block owns a 625-node subrange; adjacency never touches HBM.
__global__ __launch_bounds__(1024) void k_score_fused(const int* __restrict__ row,
                                                      const int* __restrict__ col,
                                                      const int* __restrict__ cnt,
                                                      const float* __restrict__ dis,
                                                      const float* __restrict__ scW,
                                                      const float* __restrict__ scB,
                                                      float* __restrict__ score) {
    __shared__ float dis_l[N_PER];   // 20000 B
    __shared__ int   wsum[16];       //    64 B
    __shared__ int   offs_l[SUBR];   //  2500 B
    __shared__ int   curs_l[SUBR];   //  2500 B
    __shared__ int   list[LCAP];     // 46560 B   total ~71.6 KB -> 2 blocks/CU
    int lb = swz8(blockIdx.x, 100);  // 0..799, XCD-contiguous (8 blocks of a graph share an XCD)
    int g = lb >> 3, q = lb & 7;
    int t = threadIdx.x;
    int nbase = g * N_PER;
    int ebase = g * E_PER;
    int lo = q * SUBR;

    // P1: load precomputed dis for the whole graph into LDS (float4, L2-hot)
    const float4* d4 = (const float4*)(dis + nbase);   // 20000 B offset -> 16B aligned
    for (int j4 = t; j4 < N_PER / 4; j4 += 1024) {
        float4 dv4 = d4[j4];
        int j = 4 * j4;
        dis_l[j]     = dv4.x;
        dis_l[j + 1] = dv4.y;
        dis_l[j + 2] = dv4.z;
        dis_l[j + 3] = dv4.w;
    }

    // P2: wave-shuffle inclusive scan of own-subrange degrees (3 barriers total)
    int v = (t < SUBR) ? cnt[nbase + lo + t] : 0;
    int lane = t & 63, wid = t >> 6;
    int x = v;
#pragma unroll
    for (int s = 1; s < 64; s <<= 1) {
        int o = __shfl_up(x, s, 64);
        if (lane >= s) x += o;
    }
    if (lane == 63) wsum[wid] = x;
    __syncthreads();
    if (wid == 0) {
        int ws = (lane < 16) ? wsum[lane] : 0;
#pragma unroll
        for (int s = 1; s < 16; s <<= 1) {
            int o = __shfl_up(ws, s, 64);
            if (lane >= s) ws += o;
        }
        if (lane < 16) wsum[lane] = ws;
    }
    __syncthreads();
    int incl = x + (wid > 0 ? wsum[wid - 1] : 0);
    if (t < SUBR) { offs_l[t] = incl - v + t; curs_l[t] = 0; }  // +t bank skew
    __syncthreads();

    // P3: stream graph edges (int4 col); append matches, packed (e_local<<13)|row_local
    const int4* c4 = (const int4*)(col + ebase);    // 16B-aligned
    for (int i4 = t; i4 < E_PER / 4; i4 += 1024) {
        int4 cv = c4[i4];
        int i0 = 4 * i4;
#pragma unroll
        for (int m = 0; m < 4; m++) {
            int cl = ((m == 0) ? cv.x : (m == 1) ? cv.y : (m == 2) ? cv.z : cv.w) - nbase;
            unsigned d = (unsigned)(cl - lo);
            if (d < (unsigned)SUBR) {
                int i = i0 + m;
                int slot = atomicAdd(&curs_l[d], 1);
                int pos = offs_l[d] + slot;
                if (pos < LCAP) list[pos] = (i << 13) | (row[ebase + i] - nbase);
            }
        }
    }
    __syncthreads();

    // P4: insertion sort ascending edge id (reference accumulation order), bit-exact fold
    if (t < SUBR) {
        int base = offs_l[t];
        int k = v;
        if (base + k > LCAP) k = 0;          // overflow guard (probability ~0)
        for (int i = 1; i < k; i++) {
            int key = list[base + i];
            int j = i - 1;
            while (j >= 0 && list[base + j] > key) { list[base + j + 1] = list[base + j]; j--; }
            list[base + j + 1] = key;
        }
        float w = scW[0];
        float dv = dis_l[lo + t];
        float s = 0.0f;
        for (int i = 0; i < k; i++) {
            int rl = list[base + i] & 8191;
            s = __fadd_rn(s, __fmul_rn(w, __fmul_rn(dis_l[rl], dv)));
        }
        s = __fadd_rn(s, __fmul_rn(w, __fmul_rn(dv, dv)));  // self-loop term
        s = __fadd_rn(s, scB[0]);
        score[nbase + lo + t] = s;
    }
}

// ---------------- per-graph stable top-k: register-blocked bitonic sort ----------------
// u64 key = (~sortable(score) << 32) | idx  ->  ascending u64 == descending score,
// ties broken by lower index (jax.lax.top_k semantics).
__global__ __launch_bounds__(1024) void k_topk(const float* __restrict__ score,
                                               float* __restrict__ out_batch,
                                               float* __restrict__ out_perm,
                                               int* __restrict__ perm_i,
                                               int* __restrict__ n_idx) {
    __shared__ unsigned long long keys[M + (M >> 3)];  // 9216 u64 = 73728 B (padded)
    int b = blockIdx.x, t = threadIdx.x;
    int base = 8 * t;

    // load 8 contiguous elements into registers, build keys
    unsigned long long v[8];
    if (t < 625) {   // 8*625 = 5000 = N_PER exactly
        const float4* s4 = (const float4*)(score + b * N_PER + base);
        float4 f0 = s4[0], f1 = s4[1];
        float fs[8] = {f0.x, f0.y, f0.z, f0.w, f1.x, f1.y, f1.z, f1.w};
#pragma unroll
        for (int m = 0; m < 8; m++) {
            unsigned u = __float_as_uint(fs[m]);
            unsigned asc = u ^ ((u & 0x80000000u) ? 0xFFFFFFFFu : 0x80000000u);
            v[m] = ((unsigned long long)(~asc) << 32) | (unsigned)(base + m);
        }
    } else {
#pragma unroll
        for (int m = 0; m < 8; m++) v[m] = ~0ull;  // padding sorts last
    }

#define CEV(x, y, up) { if ((v[x] > v[y]) == (up)) { unsigned long long tmp = v[x]; v[x] = v[y]; v[y] = tmp; } }
    // in-register bitonic stages k=2,4,8 (directions from global position 8t+m)
    CEV(0, 1, true)  CEV(2, 3, false) CEV(4, 5, true)  CEV(6, 7, false)      // k=2
    CEV(0, 2, true)  CEV(1, 3, true)  CEV(4, 6, false) CEV(5, 7, false)      // k=4 j=2
    CEV(0, 1, true)  CEV(2, 3, true)  CEV(4, 5, false) CEV(6, 7, false)      // k=4 j=1
    {
        bool u8 = ((t & 1) == 0);                                            // k=8
        CEV(0, 4, u8) CEV(1, 5, u8) CEV(2, 6, u8) CEV(3, 7, u8)
        CEV(0, 2, u8) CEV(1, 3, u8) CEV(4, 6, u8) CEV(5, 7, u8)
        CEV(0, 1, u8) CEV(2, 3, u8) CEV(4, 5, u8) CEV(6, 7, u8)
    }
#pragma unroll
    for (int m = 0; m < 8; m++) keys[ph(base + m)] = v[m];
    __syncthreads();

    // stages k=16..8192: LDS passes j=k/2..8, then fused register pass j=4,2,1.
    // Final stage: after j=4096 the lower half holds the 4096 smallest keys; sort only it.
    for (int k = 16; k <= M; k <<= 1) {
        bool last = (k == M);
        for (int j = k >> 1; j >= 8; j >>= 1) {
            int np = (last && j < (M >> 1)) ? (M >> 2) : (M >> 1);
            for (int p = t; p < np; p += 1024) {
                int i = ((p & ~(j - 1)) << 1) | (p & (j - 1));
                int ip = i | j;
                bool up = ((i & k) == 0);
                unsigned long long a = keys[ph(i)];
                unsigned long long c = keys[ph(ip)];
                if ((a > c) == up) { keys[ph(i)] = c; keys[ph(ip)] = a; }
            }
            __syncthreads();
        }
        int nb = last ? 512 : 1024;   // last stage: register pass only on [0,4096)
        if (t < nb) {
            bool up = ((base & k) == 0);
            unsigned long long w[8];
#pragma unroll
            for (int m = 0; m < 8; m++) w[m] = keys[ph(base + m)];
#define CEW(x, y) { if ((w[x] > w[y]) == up) { unsigned long long tmp = w[x]; w[x] = w[y]; w[y] = tmp; } }
            CEW(0, 4) CEW(1, 5) CEW(2, 6) CEW(3, 7)   // j=4
            CEW(0, 2) CEW(1, 3) CEW(4, 6) CEW(5, 7)   // j=2
            CEW(0, 1) CEW(2, 3) CEW(4, 5) CEW(6, 7)   // j=1
#pragma unroll
            for (int m = 0; m < 8; m++) keys[ph(base + m)] = w[m];
        }
        __syncthreads();
    }

    for (int r = t; r < K_PER; r += 1024) {
        unsigned long long key = keys[ph(r)];
        int idx = (int)(key & 0xFFFFFFFFull);
        int gl = b * N_PER + idx;
        int ni = b * K_PER + r;
        perm_i[ni] = gl;
        n_idx[gl] = ni;
        out_perm[ni] = (float)gl;
        out_batch[ni] = (float)b;
    }
}

// ---------------- x_new = x[perm] * tanh(score[perm]) ----------------
__global__ void k_xnew(const float4* __restrict__ x4, const float* __restrict__ score,
                       const int* __restrict__ perm_i, float4* __restrict__ out4) {
    int tid = blockIdx.x * blockDim.x + threadIdx.x;
    if (tid >= NK * (D_HID / 4)) return;
    int i = tid >> 5;       // row (D_HID/4 = 32 float4 per row)
    int c = tid & 31;
    int g = perm_i[i];
    float ts = tanhf(score[g]);
    float4 v = x4[(long)g * 32 + c];
    v.x *= ts; v.y *= ts; v.z *= ts; v.w *= ts;
    out4[tid] = v;
}

// ---------------- prefill edge outputs with -1 (no deps) ----------------
__global__ void k_prefill(float4* __restrict__ oe0, float4* __restrict__ oe1) {
    int i = blockIdx.x * blockDim.x + threadIdx.x;
    int stride = gridDim.x * blockDim.x;
    float4 m1 = make_float4(-1.0f, -1.0f, -1.0f, -1.0f);
    for (; i < E / 4; i += stride) { oe0[i] = m1; oe1[i] = m1; }
}

// ---------------- single-pass order-preserving edge compaction (decoupled lookback) ----------------
__global__ __launch_bounds__(256) void k_compact(const int* __restrict__ row,
                                                 const int* __restrict__ col,
                                                 const int* __restrict__ n_idx,
                                                 unsigned long long* __restrict__ status,
                                                 float* __restrict__ oe0,
                                                 float* __restrict__ oe1) {
    __shared__ int sh[256];
    __shared__ int excl_sh;
    int blk = blockIdx.x, t = threadIdx.x;
    int base = blk * EPB + t * EPT;
    int rr[EPT], cc[EPT];
    int cnt = 0;
#pragma unroll
    for (int i = 0; i < EPT; i++) {
        int e = base + i;
        int rv = -1, cv = -1;
        if (e < E) { rv = n_idx[row[e]]; cv = n_idx[col[e]]; }
        rr[i] = rv; cc[i] = cv;
        if (rv >= 0 && cv >= 0) cnt++;
    }
    sh[t] = cnt;
    __syncthreads();
    for (int s = 1; s < 256; s <<= 1) {
        int a = (t >= s) ? sh[t - s] : 0;
        __syncthreads();
        sh[t] += a;
        __syncthreads();
    }
    int incl = sh[t];
    int agg  = sh[255];
    if (t == 0) {
        if (blk == 0) {
            atomicExch(&status[0], FLG_I | (unsigned long long)(unsigned)agg);
            excl_sh = 0;
        } else {
            atomicExch(&status[blk], FLG_A | (unsigned long long)(unsigned)agg);
            unsigned long long ex = 0;
            for (int i = blk - 1; i >= 0; i--) {
                unsigned long long sv;
                do { sv = atomicAdd(&status[i], 0ull); } while (sv == 0ull);
                ex += (sv & 0xFFFFFFFFull);
                if (sv & FLG_I) break;
            }
            atomicExch(&status[blk], FLG_I | (ex + (unsigned long long)(unsigned)agg));
            excl_sh = (int)ex;
        }
    }
    __syncthreads();
    int pos = excl_sh + incl - cnt;
#pragma unroll
    for (int i = 0; i < EPT; i++) {
        if (rr[i] >= 0 && cc[i] >= 0) {
            oe0[pos] = (float)rr[i];
            oe1[pos] = (float)cc[i];
            pos++;
        }
    }
}

extern "C" void kernel_launch(void* const* d_in, const int* in_sizes, int n_in,
                              void* d_out, int out_size, void* d_ws, size_t ws_size,
                              hipStream_t stream) {
    const float* x   = (const float*)d_in[0];
    const float* scW = (const float*)d_in[4];
    const float* scB = (const float*)d_in[5];
    const int*   edge = (const int*)d_in[6];
    const int*   row = edge;
    const int*   col = edge + E;

    // workspace layout: status (u64, 8B-aligned at base) then ints/floats
    unsigned long long* status = (unsigned long long*)d_ws;   // NBLK_E
    int*   ws_i    = (int*)(status + NBLK_E);
    int*   deg_cnt = ws_i;                   // N
    float* dis     = (float*)(ws_i + N);     // N
    float* score   = (float*)(ws_i + 2 * N); // N
    int*   n_idx   = ws_i + 3 * N;           // N
    int*   perm_i  = ws_i + 4 * N;           // NK

    // output layout: x_new [NK, D_HID] | edge_new [2, E] | batch_new [NK] | perm [NK]
    float* out_x     = (float*)d_out;
    float* oe0       = out_x + (size_t)NK * D_HID;
    float* oe1       = oe0 + E;
    float* out_batch = oe1 + E;
    float* out_perm  = out_batch + NK;

    hipMemsetAsync(deg_cnt, 0, (size_t)N * sizeof(int), stream);
    hipMemsetAsync(n_idx, 0xFF, (size_t)N * sizeof(int), stream);  // -1
    hipMemsetAsync(status, 0, (size_t)NBLK_E * sizeof(unsigned long long), stream);

    k_prefill<<<2048, 256, 0, stream>>>((float4*)oe0, (float4*)oe1);
    k_count<<<200, 1024, 0, stream>>>(col, deg_cnt);
    k_dis<<<(N + 255) / 256, 256, 0, stream>>>(deg_cnt, dis);
    k_score_fused<<<800, 1024, 0, stream>>>(row, col, deg_cnt, dis, scW, scB, score);
    k_topk<<<B, 1024, 0, stream>>>(score, out_batch, out_perm, perm_i, n_idx);
    k_xnew<<<(NK * (D_HID / 4) + 255) / 256, 256, 0, stream>>>((const float4*)x, score, perm_i,
                                                               (float4*)out_x);
    k_compact<<<NBLK_E, 256, 0, stream>>>(row, col, n_idx, status, oe0, oe1);
}

// Round 10
// 257.822 us; speedup vs baseline: 2.7879x; 1.3028x over previous
//
#include <hip/hip_runtime.h>
#include <hip/hip_bf16.h>

// Problem constants (fixed-size problem)
constexpr int H      = 4;
constexpr int D_SUB  = 32;
constexpr int D_HID  = 128;
constexpr int B      = 100;
constexpr int N_PER  = 5000;
constexpr int N      = B * N_PER;        // 500000
constexpr int DEG    = 16;
constexpr int E      = N * DEG;          // 8000000
constexpr int E_PER  = N_PER * DEG;      // 80000
constexpr int K_PER  = 2500;
constexpr int NK     = B * K_PER;        // 250000

constexpr int EPB    = 4096;             // edges per block (compaction)
constexpr int EPT    = 16;               // edges per thread (compaction)
constexpr int NBLK_E = (E + EPB - 1) / EPB; // 1954

constexpr int SUBR   = 625;              // nodes per fused-score block (8 blocks/graph)
constexpr int LCAP   = 11640;            // LDS edge-list capacity (mean 10000 + skew 625 + slack)

constexpr int M      = 8192;             // bitonic size (pow2 >= N_PER)

// decoupled-lookback status flags
constexpr unsigned long long FLG_A = 1ull << 62;   // aggregate ready
constexpr unsigned long long FLG_I = 2ull << 62;   // inclusive ready

// bijective XCD-chunked block swizzle: grid must be a multiple of 8
__device__ __forceinline__ int swz8(int bid, int chunk) {
    return (bid & 7) * chunk + (bid >> 3);
}

// padded LDS index for u64 keys: +1 slot per 8 -> breaks 64B-stride bank aliasing
__device__ __forceinline__ int ph(int i) { return i + (i >> 3); }

// ---------------- in-degree count: per-graph-half LDS histogram, plain stores ----------------
// Block (g, half) owns cnt2[half*N + g*N_PER .. +N_PER) exclusively -> no memset, no atomics.
__global__ __launch_bounds__(1024) void k_count(const int* __restrict__ col,
                                                int* __restrict__ cnt2) {
    __shared__ int h[N_PER];  // 20 KB
    int lb = swz8(blockIdx.x, 25);       // 0..199, XCD-contiguous graphs
    int g = lb >> 1, half = lb & 1;
    for (int i = threadIdx.x; i < N_PER; i += 1024) h[i] = 0;
    __syncthreads();
    int ebase = g * E_PER + half * (E_PER / 2);
    int nbase = g * N_PER;
    const int4* c4 = (const int4*)(col + ebase);    // 16B-aligned (ebase*4 % 16 == 0)
    for (int i = threadIdx.x; i < E_PER / 2 / 4; i += 1024) {
        int4 v = c4[i];
        atomicAdd(&h[v.x - nbase], 1);
        atomicAdd(&h[v.y - nbase], 1);
        atomicAdd(&h[v.z - nbase], 1);
        atomicAdd(&h[v.w - nbase], 1);
    }
    __syncthreads();
    int* dst = cnt2 + half * N + nbase;
    for (int i = threadIdx.x; i < N_PER; i += 1024) dst[i] = h[i];
}

// ---------------- deg = halves sum; dis = (1+deg)^-0.5 (XLA pow(x,-0.5)->1/sqrt) ----------------
__global__ void k_dis(const int* __restrict__ cnt2, int* __restrict__ cnt,
                      float* __restrict__ dis) {
    int v = blockIdx.x * blockDim.x + threadIdx.x;
    if (v < N) {
        int c = cnt2[v] + cnt2[N + v];
        cnt[v] = c;
        float d = (float)(1 + c);
        dis[v] = __fdiv_rn(1.0f, __fsqrt_rn(d));
    }
}

// ---------------- fused: adjacency-in-LDS + bit-exact score ----------------
// 8 blocks per graph; block owns a 625-node subrange; adjacency never touches HBM.
__global__ __launch_bounds__(1024) void k_score_fused(const int* __restrict__ row,
                                                      const int* __restrict__ col,
                                                      const int* __restrict__ cnt,
                                                      const float* __restrict__ dis,
                                                      const float* __restrict__ scW,
                                                      const float* __restrict__ scB,
                                                      float* __restrict__ score) {
    __shared__ float dis_l[N_PER];   // 20000 B
    __shared__ int   wsum[16];       //    64 B
    __shared__ int   offs_l[SUBR];   //  2500 B
    __shared__ int   curs_l[SUBR];   //  2500 B
    __shared__ int   list[LCAP];     // 46560 B   total ~71.6 KB -> 2 blocks/CU
    int lb = swz8(blockIdx.x, 100);  // 0..799, XCD-contiguous (8 blocks of a graph share an XCD)
    int g = lb >> 3, q = lb & 7;
    int t = threadIdx.x;
    int nbase = g * N_PER;
    int ebase = g * E_PER;
    int lo = q * SUBR;

    // P1: load precomputed dis for the whole graph into LDS (float4, L2-hot)
    const float4* d4 = (const float4*)(dis + nbase);   // 20000 B offset -> 16B aligned
    for (int j4 = t; j4 < N_PER / 4; j4 += 1024) {
        float4 dv4 = d4[j4];
        int j = 4 * j4;
        dis_l[j]     = dv4.x;
        dis_l[j + 1] = dv4.y;
        dis_l[j + 2] = dv4.z;
        dis_l[j + 3] = dv4.w;
    }

    // P2: wave-shuffle inclusive scan of own-subrange degrees (3 barriers total)
    int v = (t < SUBR) ? cnt[nbase + lo + t] : 0;
    int lane = t & 63, wid = t >> 6;
    int x = v;
#pragma unroll
    for (int s = 1; s < 64; s <<= 1) {
        int o = __shfl_up(x, s, 64);
        if (lane >= s) x += o;
    }
    if (lane == 63) wsum[wid] = x;
    __syncthreads();
    if (wid == 0) {
        int ws = (lane < 16) ? wsum[lane] : 0;
#pragma unroll
        for (int s = 1; s < 16; s <<= 1) {
            int o = __shfl_up(ws, s, 64);
            if (lane >= s) ws += o;
        }
        if (lane < 16) wsum[lane] = ws;
    }
    __syncthreads();
    int incl = x + (wid > 0 ? wsum[wid - 1] : 0);
    if (t < SUBR) { offs_l[t] = incl - v + t; curs_l[t] = 0; }  // +t bank skew
    __syncthreads();

    // P3: stream graph edges (int4 col AND row, both coalesced); append matches,
    // packed (e_local<<13)|row_local — no scattered scalar gathers.
    const int4* c4 = (const int4*)(col + ebase);    // 16B-aligned
    const int4* r4 = (const int4*)(row + ebase);
    for (int i4 = t; i4 < E_PER / 4; i4 += 1024) {
        int4 cv = c4[i4];
        int4 rv = r4[i4];
        int i0 = 4 * i4;
#pragma unroll
        for (int m = 0; m < 4; m++) {
            int cl = ((m == 0) ? cv.x : (m == 1) ? cv.y : (m == 2) ? cv.z : cv.w) - nbase;
            int rl = ((m == 0) ? rv.x : (m == 1) ? rv.y : (m == 2) ? rv.z : rv.w) - nbase;
            unsigned d = (unsigned)(cl - lo);
            if (d < (unsigned)SUBR) {
                int i = i0 + m;
                int slot = atomicAdd(&curs_l[d], 1);
                int pos = offs_l[d] + slot;
                if (pos < LCAP) list[pos] = (i << 13) | rl;
            }
        }
    }
    __syncthreads();

    // P4: insertion sort ascending edge id (reference accumulation order), bit-exact fold
    if (t < SUBR) {
        int base = offs_l[t];
        int k = v;
        if (base + k > LCAP) k = 0;          // overflow guard (probability ~0)
        for (int i = 1; i < k; i++) {
            int key = list[base + i];
            int j = i - 1;
            while (j >= 0 && list[base + j] > key) { list[base + j + 1] = list[base + j]; j--; }
            list[base + j + 1] = key;
        }
        float w = scW[0];
        float dv = dis_l[lo + t];
        float s = 0.0f;
        for (int i = 0; i < k; i++) {
            int rl = list[base + i] & 8191;
            s = __fadd_rn(s, __fmul_rn(w, __fmul_rn(dis_l[rl], dv)));
        }
        s = __fadd_rn(s, __fmul_rn(w, __fmul_rn(dv, dv)));  // self-loop term
        s = __fadd_rn(s, scB[0]);
        score[nbase + lo + t] = s;
    }
}

// ---------------- per-graph stable top-k: register-blocked bitonic sort ----------------
// u64 key = (~sortable(score) << 32) | idx  ->  ascending u64 == descending score,
// ties broken by lower index (jax.lax.top_k semantics).
__global__ __launch_bounds__(1024) void k_topk(const float* __restrict__ score,
                                               float* __restrict__ out_batch,
                                               float* __restrict__ out_perm,
                                               int* __restrict__ perm_i,
                                               int* __restrict__ n_idx) {
    __shared__ unsigned long long keys[M + (M >> 3)];  // 9216 u64 = 73728 B (padded)
    int b = blockIdx.x, t = threadIdx.x;
    int base = 8 * t;

    // load 8 contiguous elements into registers, build keys
    unsigned long long v[8];
    if (t < 625) {   // 8*625 = 5000 = N_PER exactly
        const float4* s4 = (const float4*)(score + b * N_PER + base);
        float4 f0 = s4[0], f1 = s4[1];
        float fs[8] = {f0.x, f0.y, f0.z, f0.w, f1.x, f1.y, f1.z, f1.w};
#pragma unroll
        for (int m = 0; m < 8; m++) {
            unsigned u = __float_as_uint(fs[m]);
            unsigned asc = u ^ ((u & 0x80000000u) ? 0xFFFFFFFFu : 0x80000000u);
            v[m] = ((unsigned long long)(~asc) << 32) | (unsigned)(base + m);
        }
    } else {
#pragma unroll
        for (int m = 0; m < 8; m++) v[m] = ~0ull;  // padding sorts last
    }

#define CEV(x, y, up) { if ((v[x] > v[y]) == (up)) { unsigned long long tmp = v[x]; v[x] = v[y]; v[y] = tmp; } }
    // in-register bitonic stages k=2,4,8 (directions from global position 8t+m)
    CEV(0, 1, true)  CEV(2, 3, false) CEV(4, 5, true)  CEV(6, 7, false)      // k=2
    CEV(0, 2, true)  CEV(1, 3, true)  CEV(4, 6, false) CEV(5, 7, false)      // k=4 j=2
    CEV(0, 1, true)  CEV(2, 3, true)  CEV(4, 5, false) CEV(6, 7, false)      // k=4 j=1
    {
        bool u8 = ((t & 1) == 0);                                            // k=8
        CEV(0, 4, u8) CEV(1, 5, u8) CEV(2, 6, u8) CEV(3, 7, u8)
        CEV(0, 2, u8) CEV(1, 3, u8) CEV(4, 6, u8) CEV(5, 7, u8)
        CEV(0, 1, u8) CEV(2, 3, u8) CEV(4, 5, u8) CEV(6, 7, u8)
    }
#pragma unroll
    for (int m = 0; m < 8; m++) keys[ph(base + m)] = v[m];
    __syncthreads();

    // stages k=16..8192: LDS passes j=k/2..8, then fused register pass j=4,2,1.
    // Final stage: after j=4096 the lower half holds the 4096 smallest keys; sort only it.
    for (int k = 16; k <= M; k <<= 1) {
        bool last = (k == M);
        for (int j = k >> 1; j >= 8; j >>= 1) {
            int np = (last && j < (M >> 1)) ? (M >> 2) : (M >> 1);
            for (int p = t; p < np; p += 1024) {
                int i = ((p & ~(j - 1)) << 1) | (p & (j - 1));
                int ip = i | j;
                bool up = ((i & k) == 0);
                unsigned long long a = keys[ph(i)];
                unsigned long long c = keys[ph(ip)];
                if ((a > c) == up) { keys[ph(i)] = c; keys[ph(ip)] = a; }
            }
            __syncthreads();
        }
        int nb = last ? 512 : 1024;   // last stage: register pass only on [0,4096)
        if (t < nb) {
            bool up = ((base & k) == 0);
            unsigned long long w[8];
#pragma unroll
            for (int m = 0; m < 8; m++) w[m] = keys[ph(base + m)];
#define CEW(x, y) { if ((w[x] > w[y]) == up) { unsigned long long tmp = w[x]; w[x] = w[y]; w[y] = tmp; } }
            CEW(0, 4) CEW(1, 5) CEW(2, 6) CEW(3, 7)   // j=4
            CEW(0, 2) CEW(1, 3) CEW(4, 6) CEW(5, 7)   // j=2
            CEW(0, 1) CEW(2, 3) CEW(4, 5) CEW(6, 7)   // j=1
#pragma unroll
            for (int m = 0; m < 8; m++) keys[ph(base + m)] = w[m];
        }
        __syncthreads();
    }

    for (int r = t; r < K_PER; r += 1024) {
        unsigned long long key = keys[ph(r)];
        int idx = (int)(key & 0xFFFFFFFFull);
        int gl = b * N_PER + idx;
        int ni = b * K_PER + r;
        perm_i[ni] = gl;
        n_idx[gl] = ni;
        out_perm[ni] = (float)gl;
        out_batch[ni] = (float)b;
    }
}

// ---------------- x_new = x[perm] * tanh(score[perm]) ----------------
__global__ void k_xnew(const float4* __restrict__ x4, const float* __restrict__ score,
                       const int* __restrict__ perm_i, float4* __restrict__ out4) {
    int tid = blockIdx.x * blockDim.x + threadIdx.x;
    if (tid >= NK * (D_HID / 4)) return;
    int i = tid >> 5;       // row (D_HID/4 = 32 float4 per row)
    int c = tid & 31;
    int g = perm_i[i];
    float ts = tanhf(score[g]);
    float4 v = x4[(long)g * 32 + c];
    v.x *= ts; v.y *= ts; v.z *= ts; v.w *= ts;
    out4[tid] = v;
}

// ---------------- prefill: edge outputs = -1, n_idx = -1, status = 0 (no deps) ----------------
__global__ void k_prefill(float4* __restrict__ oe0, float4* __restrict__ oe1,
                          int4* __restrict__ n_idx4,
                          unsigned long long* __restrict__ status) {
    int i = blockIdx.x * blockDim.x + threadIdx.x;
    int stride = gridDim.x * blockDim.x;
    float4 m1 = make_float4(-1.0f, -1.0f, -1.0f, -1.0f);
    for (int j = i; j < E / 4; j += stride) { oe0[j] = m1; oe1[j] = m1; }
    int4 mi = make_int4(-1, -1, -1, -1);
    for (int j = i; j < N / 4; j += stride) n_idx4[j] = mi;
    for (int j = i; j < NBLK_E; j += stride) status[j] = 0ull;
}

// ---------------- single-pass order-preserving edge compaction (decoupled lookback) ----------------
__global__ __launch_bounds__(256) void k_compact(const int* __restrict__ row,
                                                 const int* __restrict__ col,
                                                 const int* __restrict__ n_idx,
                                                 unsigned long long* __restrict__ status,
                                                 float* __restrict__ oe0,
                                                 float* __restrict__ oe1) {
    __shared__ int sh[256];
    __shared__ int excl_sh;
    int blk = blockIdx.x, t = threadIdx.x;
    int base = blk * EPB + t * EPT;
    int rr[EPT], cc[EPT];
    int cnt = 0;
    if (blk < NBLK_E - 1) {
        // full block: int4 fast path (base is 16-int aligned)
#pragma unroll
        for (int i4 = 0; i4 < 4; i4++) {
            int4 rv = ((const int4*)(row + base))[i4];
            int4 cv = ((const int4*)(col + base))[i4];
            rr[4 * i4 + 0] = n_idx[rv.x];  cc[4 * i4 + 0] = n_idx[cv.x];
            rr[4 * i4 + 1] = n_idx[rv.y];  cc[4 * i4 + 1] = n_idx[cv.y];
            rr[4 * i4 + 2] = n_idx[rv.z];  cc[4 * i4 + 2] = n_idx[cv.z];
            rr[4 * i4 + 3] = n_idx[rv.w];  cc[4 * i4 + 3] = n_idx[cv.w];
        }
#pragma unroll
        for (int i = 0; i < EPT; i++)
            if (rr[i] >= 0 && cc[i] >= 0) cnt++;
    } else {
        // ragged last block: scalar guarded path
#pragma unroll
        for (int i = 0; i < EPT; i++) {
            int e = base + i;
            int rv = -1, cv = -1;
            if (e < E) { rv = n_idx[row[e]]; cv = n_idx[col[e]]; }
            rr[i] = rv; cc[i] = cv;
            if (rv >= 0 && cv >= 0) cnt++;
        }
    }
    sh[t] = cnt;
    __syncthreads();
    for (int s = 1; s < 256; s <<= 1) {
        int a = (t >= s) ? sh[t - s] : 0;
        __syncthreads();
        sh[t] += a;
        __syncthreads();
    }
    int incl = sh[t];
    int agg  = sh[255];
    if (t == 0) {
        if (blk == 0) {
            atomicExch(&status[0], FLG_I | (unsigned long long)(unsigned)agg);
            excl_sh = 0;
        } else {
            atomicExch(&status[blk], FLG_A | (unsigned long long)(unsigned)agg);
            unsigned long long ex = 0;
            for (int i = blk - 1; i >= 0; i--) {
                unsigned long long sv;
                do { sv = atomicAdd(&status[i], 0ull); } while (sv == 0ull);
                ex += (sv & 0xFFFFFFFFull);
                if (sv & FLG_I) break;
            }
            atomicExch(&status[blk], FLG_I | (ex + (unsigned long long)(unsigned)agg));
            excl_sh = (int)ex;
        }
    }
    __syncthreads();
    int pos = excl_sh + incl - cnt;
#pragma unroll
    for (int i = 0; i < EPT; i++) {
        if (rr[i] >= 0 && cc[i] >= 0) {
            oe0[pos] = (float)rr[i];
            oe1[pos] = (float)cc[i];
            pos++;
        }
    }
}

extern "C" void kernel_launch(void* const* d_in, const int* in_sizes, int n_in,
                              void* d_out, int out_size, void* d_ws, size_t ws_size,
                              hipStream_t stream) {
    const float* x   = (const float*)d_in[0];
    const float* scW = (const float*)d_in[4];
    const float* scB = (const float*)d_in[5];
    const int*   edge = (const int*)d_in[6];
    const int*   row = edge;
    const int*   col = edge + E;

    // workspace layout: status (u64, 8B-aligned at base) then ints/floats
    unsigned long long* status = (unsigned long long*)d_ws;   // NBLK_E
    int*   ws_i    = (int*)(status + NBLK_E);
    int*   cnt2    = ws_i;                   // 2N (half histograms)
    int*   deg_cnt = ws_i + 2 * N;           // N  (summed)
    float* dis     = (float*)(ws_i + 3 * N); // N
    float* score   = (float*)(ws_i + 4 * N); // N
    int*   n_idx   = ws_i + 5 * N;           // N
    int*   perm_i  = ws_i + 6 * N;           // NK

    // output layout: x_new [NK, D_HID] | edge_new [2, E] | batch_new [NK] | perm [NK]
    float* out_x     = (float*)d_out;
    float* oe0       = out_x + (size_t)NK * D_HID;
    float* oe1       = oe0 + E;
    float* out_batch = oe1 + E;
    float* out_perm  = out_batch + NK;

    k_prefill<<<2048, 256, 0, stream>>>((float4*)oe0, (float4*)oe1, (int4*)n_idx, status);
    k_count<<<200, 1024, 0, stream>>>(col, cnt2);
    k_dis<<<(N + 255) / 256, 256, 0, stream>>>(cnt2, deg_cnt, dis);
    k_score_fused<<<800, 1024, 0, stream>>>(row, col, deg_cnt, dis, scW, scB, score);
    k_topk<<<B, 1024, 0, stream>>>(score, out_batch, out_perm, perm_i, n_idx);
    k_xnew<<<(NK * (D_HID / 4) + 255) / 256, 256, 0, stream>>>((const float4*)x, score, perm_i,
                                                               (float4*)out_x);
    k_compact<<<NBLK_E, 256, 0, stream>>>(row, col, n_idx, status, oe0, oe1);
}